// Round 3
// baseline (59.550 us; speedup 1.0000x reference)
//
#include <hip/hip_runtime.h>

// Problem constants
#define NB 64
#define NL 128
#define NQ 128
#define NE 16384

// ws float layout
#define WS_WT   0          // [j][i] 128x128: WT[j*128+i] = W[i][j]
#define WS_A    16384      // [p][q] 128x128 plain A_fid
#define WS_TW   32768      // total weight (written by prep)
#define WS_NUM  32769      // numerator accumulator (zeroed by prep)
#define WS_CNT  32770      // int ticket counter (zeroed by prep)

// ---------------------------------------------------------------------------
// prep: block 0 scatters edge weights into LDS (64 KB) then writes W^T to ws,
// computes total weight, zeroes NUM/CNT. Blocks 1..64 build A_fid plain.
// ---------------------------------------------------------------------------
__global__ __launch_bounds__(256) void prep_kernel(const float* __restrict__ dhw,
                                                   const float* __restrict__ derr,
                                                   const int* __restrict__ pairs,
                                                   const float* __restrict__ wts,
                                                   float* __restrict__ ws) {
    const int t = threadIdx.x;
    if (blockIdx.x == 0) {
        __shared__ float Wl[NQ * NL];     // 64 KB: Wl[j*128+i]
        __shared__ float red[4];
        #pragma unroll
        for (int r = 0; r < 16; ++r)
            *(float4*)&Wl[(t + 256 * r) * 4] = make_float4(0.f, 0.f, 0.f, 0.f);
        __syncthreads();

        float tw = 0.f;
        #pragma unroll 4
        for (int r = 0; r < 32; ++r) {
            const int e2 = t + 256 * r;                       // 2-edge pack
            const int4   pr = ((const int4*)pairs)[e2];       // (i0,j0,i1,j1)
            const float2 wv = ((const float2*)wts)[e2];
            atomicAdd(&Wl[pr.y * 128 + pr.x], wv.x);
            atomicAdd(&Wl[pr.w * 128 + pr.z], wv.y);
            tw += wv.x + wv.y;
        }
        __syncthreads();

        #pragma unroll
        for (int r = 0; r < 16; ++r) {
            const int f = (t + 256 * r) * 4;
            *(float4*)&ws[WS_WT + f] = *(const float4*)&Wl[f];
        }
        #pragma unroll
        for (int off = 32; off; off >>= 1) tw += __shfl_down(tw, off, 64);
        if ((t & 63) == 0) red[t >> 6] = tw;
        __syncthreads();
        if (t == 0) {
            ws[WS_TW]  = red[0] + red[1] + red[2] + red[3];
            ws[WS_NUM] = 0.f;
            ((int*)ws)[WS_CNT] = 0;
        }
    } else {
        const int idx = (blockIdx.x - 1) * 256 + t;           // [0, 16384)
        const float hw = dhw[idx], er = derr[idx];
        ws[WS_A + idx] = (hw == 1.0f) ? fmaxf(1.0f - er, 0.f) : 0.f;
    }
}

// ---------------------------------------------------------------------------
// batch: block = (b, 32-row i-tile, 32-col q-chunk), 1024 blocks x 256 thr.
// Phase G (4x4/thread, per-wave j-split + LDS reduce):
//   G[ii][qq] = sum_j W[i0+ii][j] * Pb[j][q0+qq]
// Phase M (4x4/thread): M[p][qq] = sum_ii Pb[i0+ii][p] * G[ii][qq]
//   s = sum A[p][q0+qq] * M[p][qq]; last block finalizes the loss.
// LDS 32.8 KB -> 4 blocks/CU.
// ---------------------------------------------------------------------------
__global__ __launch_bounds__(256, 4) void batch_kernel(const float* __restrict__ P,
                                                       float* __restrict__ ws,
                                                       float* __restrict__ out) {
    const int blk = blockIdx.x;
    const int b   = blk >> 4;
    const int i0  = ((blk >> 2) & 3) * 32;
    const int q0  = (blk & 3) * 32;
    const float* __restrict__ Pb  = P + b * (NL * NQ);
    const float* __restrict__ WTg = ws + WS_WT;
    const float* __restrict__ Ag  = ws + WS_A;

    __shared__ float R1[4096];   // WT [j][ii] stride 32  ->  Pi [ii][p] stride 128
    __shared__ float R2[4096];   // Pq [j][qq] stride 32  ->  G partials / G final
    __shared__ float red[4];

    const int t = threadIdx.x;

    // Stage WT tile and Pq slab (1024 float4 each, coalesced)
    #pragma unroll
    for (int r = 0; r < 4; ++r) {
        const int f = t + 256 * r;
        const int j = f >> 3, c = (f & 7) * 4;
        *(float4*)&R1[j * 32 + c] = *(const float4*)&WTg[j * 128 + i0 + c];
        *(float4*)&R2[j * 32 + c] = *(const float4*)&Pb[j * 128 + q0 + c];
    }
    __syncthreads();

    // ---- Phase G: wave 'sub' handles j in [sub*32, sub*32+32), 4x4/thread ----
    const int sub = t >> 6, pos = t & 63;
    const int ii0 = (pos >> 3) * 4, qq0 = (pos & 7) * 4;
    float g[4][4] = {};
    const int jb = sub * 32;
    #pragma unroll 8
    for (int jj = 0; jj < 32; ++jj) {
        const int j = jb + jj;
        const float4 wv = *(const float4*)&R1[j * 32 + ii0];   // conflict-free
        const float4 pv = *(const float4*)&R2[j * 32 + qq0];   // conflict-free
        const float wa[4] = {wv.x, wv.y, wv.z, wv.w};
        const float pa[4] = {pv.x, pv.y, pv.z, pv.w};
        #pragma unroll
        for (int a = 0; a < 4; ++a)
            #pragma unroll
            for (int c = 0; c < 4; ++c)
                g[a][c] += wa[a] * pa[c];
    }
    __syncthreads();   // all R1/R2 reads done

    // Partial store: R2[sub*1024 + ii*32 + qq]
    #pragma unroll
    for (int a = 0; a < 4; ++a)
        *(float4*)&R2[sub * 1024 + (ii0 + a) * 32 + qq0] =
            make_float4(g[a][0], g[a][1], g[a][2], g[a][3]);
    __syncthreads();

    // In-place reduce into sub0 region (each thread owns one float4 cell)
    {
        const int ii = t >> 3, qc = (t & 7) * 4;
        float4 s0 = *(float4*)&R2[       ii * 32 + qc];
        const float4 s1 = *(float4*)&R2[1024 + ii * 32 + qc];
        const float4 s2 = *(float4*)&R2[2048 + ii * 32 + qc];
        const float4 s3 = *(float4*)&R2[3072 + ii * 32 + qc];
        s0.x += s1.x + s2.x + s3.x;  s0.y += s1.y + s2.y + s3.y;
        s0.z += s1.z + s2.z + s3.z;  s0.w += s1.w + s2.w + s3.w;
        *(float4*)&R2[ii * 32 + qc] = s0;     // own cell: no extra barrier
    }
    // Restage Pi rows into R1 (R1 fully consumed before last barrier)
    #pragma unroll
    for (int r = 0; r < 4; ++r) {
        const int f4 = (t + 256 * r) * 4;
        *(float4*)&R1[f4] = *(const float4*)&Pb[i0 * 128 + f4];   // coalesced
    }
    __syncthreads();

    // ---- Phase M: 4x4/thread over (p, qq) ----
    const int p0 = (t >> 3) * 4, qm = (t & 7) * 4;
    float m[4][4] = {};
    #pragma unroll 8
    for (int ii = 0; ii < 32; ++ii) {
        const float4 pv = *(const float4*)&R1[ii * 128 + p0];  // conflict-free
        const float4 gv = *(const float4*)&R2[ii * 32 + qm];   // conflict-free
        const float pa[4] = {pv.x, pv.y, pv.z, pv.w};
        const float ga[4] = {gv.x, gv.y, gv.z, gv.w};
        #pragma unroll
        for (int a = 0; a < 4; ++a)
            #pragma unroll
            for (int c = 0; c < 4; ++c)
                m[a][c] += pa[a] * ga[c];
    }

    // Dot with A (L2-hot)
    float s = 0.f;
    #pragma unroll
    for (int a = 0; a < 4; ++a) {
        const float4 av = *(const float4*)&Ag[(p0 + a) * 128 + q0 + qm];
        s += av.x * m[a][0] + av.y * m[a][1] + av.z * m[a][2] + av.w * m[a][3];
    }

    // Block reduce + fused finalize (atomic ticket; last block writes loss)
    #pragma unroll
    for (int off = 32; off; off >>= 1) s += __shfl_down(s, off, 64);
    if ((t & 63) == 0) red[t >> 6] = s;
    __syncthreads();
    if (t == 0) {
        atomicAdd(&ws[WS_NUM], red[0] + red[1] + red[2] + red[3]);
        __threadfence();
        const int old = atomicAdd((int*)ws + WS_CNT, 1);
        if (old == NB * 16 - 1) {
            const float num = atomicAdd(&ws[WS_NUM], 0.0f);   // coherent read
            const float tw  = fmaxf(ws[WS_TW], 1e-8f);
            out[0] = -num / ((float)NB * tw);
        }
    }
}

extern "C" void kernel_launch(void* const* d_in, const int* in_sizes, int n_in,
                              void* d_out, int out_size, void* d_ws, size_t ws_size,
                              hipStream_t stream) {
    const float* P    = (const float*)d_in[0];
    const float* dhw  = (const float*)d_in[1];
    const float* derr = (const float*)d_in[2];
    const int*   prs  = (const int*)d_in[3];
    const float* wts  = (const float*)d_in[4];
    float* ws  = (float*)d_ws;
    float* out = (float*)d_out;

    prep_kernel<<<65, 256, 0, stream>>>(dhw, derr, prs, wts, ws);
    batch_kernel<<<NB * 16, 256, 0, stream>>>(P, ws, out);
}

// Round 4
// 35.187 us; speedup vs baseline: 1.6924x; 1.6924x over previous
//
#include <hip/hip_runtime.h>

// Problem constants
#define NB 64
#define NL 128
#define NQ 128
#define NE 16384

// ws float layout (round-2 proven scaffold)
#define WS_WT   0          // [j][i] 128x128: WT[j*128+i] = W[i][j]
#define WS_TW   16384      // total weight
#define WS_NUM  16385      // numerator accumulator
#define WS_A    16388      // [p][q] 128x128 plain A_fid (16B aligned)
#define WS_END  (WS_A + 16384)

// ---------------------------------------------------------------------------
// prep (identical to round-2): build A_fid, scatter edge weights into W^T,
// reduce total weight. grid = 64 x 256.
// ---------------------------------------------------------------------------
__global__ void prep_kernel(const float* __restrict__ dhw,
                            const float* __restrict__ derr,
                            const int* __restrict__ pairs,
                            const float* __restrict__ wts,
                            float* __restrict__ ws) {
    const int idx = blockIdx.x * 256 + threadIdx.x;

    {
        const float hw = dhw[idx];
        const float er = derr[idx];
        ws[WS_A + idx] = (hw == 1.0f) ? fmaxf(1.0f - er, 0.f) : 0.f;
    }

    const int i = pairs[2 * idx];
    const int j = pairs[2 * idx + 1];
    const float w = wts[idx];
    atomicAdd(&ws[WS_WT + j * 128 + i], w);

    float s = w;
    #pragma unroll
    for (int off = 32; off; off >>= 1) s += __shfl_down(s, off, 64);
    __shared__ float red[4];
    const int lane = threadIdx.x & 63, wv = threadIdx.x >> 6;
    if (lane == 0) red[wv] = s;
    __syncthreads();
    if (threadIdx.x == 0)
        atomicAdd(&ws[WS_TW], red[0] + red[1] + red[2] + red[3]);
}

// ---------------------------------------------------------------------------
// batch: block = (b, 32-row i-tile, 64-col q-half); 512 blocks x 512 threads.
// Lanes span q (qq = lane). Wave-uniform factors (W rows, Pi rows) are read
// as single broadcast ds_read_b128 -> LDS traffic ~0.5 B/FMA, VALU-bound.
//   Phase G: G[ii][qq] = sum_j W[i0+ii][j] * Pb[j][q0+qq]   (wave: 4 ii rows)
//   Phase M: M[p][qq]  = sum_ii Pi[ii][p]  * G[ii][qq]      (wave: 16 p rows)
//   s = sum A[p][q0+qq] * M[p][qq]
// LDS 57.4 KB -> 2 blocks/CU; grid 512 = exactly 2/CU (16 waves/CU).
// ---------------------------------------------------------------------------
__global__ __launch_bounds__(512, 4) void batch_kernel(const float* __restrict__ P,
                                                       float* __restrict__ ws) {
    const int blk = blockIdx.x;
    const int b   = blk >> 3;
    const int i0  = ((blk >> 1) & 3) * 32;
    const int q0  = (blk & 1) * 64;
    const float* __restrict__ Pb  = P + b * (NL * NQ);
    const float* __restrict__ WTg = ws + WS_WT;
    const float* __restrict__ Ag  = ws + WS_A;

    __shared__ float Wl[128 * 32];   // [j][ii] 16 KB; reused as Pi [ii][p] 32x128
    __shared__ float Pq[128 * 64];   // [j][qq] 32 KB
    __shared__ float G [32 * 64];    // [ii][qq] 8 KB
    __shared__ float red[8];

    const int t    = threadIdx.x;
    const int w    = t >> 6;         // wave 0..7
    const int lane = t & 63;         // qq = lane

    // Stage W tile [j][ii] and Pq slab [j][qq] (float4, coalesced)
    #pragma unroll
    for (int r = 0; r < 2; ++r) {
        const int f = t + 512 * r;                  // [0,1024)
        const int j = f >> 3, c = (f & 7) * 4;
        *(float4*)&Wl[j * 32 + c] = *(const float4*)&WTg[j * 128 + i0 + c];
    }
    #pragma unroll
    for (int r = 0; r < 4; ++r) {
        const int f = t + 512 * r;                  // [0,2048)
        const int j = f >> 4, c = (f & 15) * 4;
        *(float4*)&Pq[j * 64 + c] = *(const float4*)&Pb[j * 128 + q0 + c];
    }
    __syncthreads();

    // ---- Phase G: wave w owns ii in [w*4, w*4+4); qq = lane ----
    float g0 = 0.f, g1 = 0.f, g2 = 0.f, g3 = 0.f;
    #pragma unroll 4
    for (int j = 0; j < NL; ++j) {
        const float4 wv = *(const float4*)&Wl[j * 32 + w * 4];  // uniform bcast
        const float  pv = Pq[j * 64 + lane];                    // per-lane, 2-way free
        g0 += wv.x * pv; g1 += wv.y * pv; g2 += wv.z * pv; g3 += wv.w * pv;
    }
    G[(w * 4 + 0) * 64 + lane] = g0;
    G[(w * 4 + 1) * 64 + lane] = g1;
    G[(w * 4 + 2) * 64 + lane] = g2;
    G[(w * 4 + 3) * 64 + lane] = g3;
    __syncthreads();                 // Wl fully consumed; G complete

    // Restage Pi = Pb[i0..i0+31][0..127] over the Wl region (flat coalesced)
    float* Pi = Wl;                  // [ii][p] stride 128
    #pragma unroll
    for (int r = 0; r < 2; ++r) {
        const int f4 = (t + 512 * r) * 4;           // [0,4096) floats
        *(float4*)&Pi[f4] = *(const float4*)&Pb[i0 * 128 + f4];
    }
    __syncthreads();

    // ---- Phase M: wave w owns p in [w*16, w*16+16); qq = lane ----
    const int pw = w * 16;
    float m[16] = {};
    #pragma unroll 2
    for (int ii = 0; ii < 32; ++ii) {
        const float  gv = G[ii * 64 + lane];                        // per-lane
        const float4 a0 = *(const float4*)&Pi[ii * 128 + pw + 0];   // uniform bcast
        const float4 a1 = *(const float4*)&Pi[ii * 128 + pw + 4];
        const float4 a2 = *(const float4*)&Pi[ii * 128 + pw + 8];
        const float4 a3 = *(const float4*)&Pi[ii * 128 + pw + 12];
        m[0]  += a0.x * gv; m[1]  += a0.y * gv; m[2]  += a0.z * gv; m[3]  += a0.w * gv;
        m[4]  += a1.x * gv; m[5]  += a1.y * gv; m[6]  += a1.z * gv; m[7]  += a1.w * gv;
        m[8]  += a2.x * gv; m[9]  += a2.y * gv; m[10] += a2.z * gv; m[11] += a2.w * gv;
        m[12] += a3.x * gv; m[13] += a3.y * gv; m[14] += a3.z * gv; m[15] += a3.w * gv;
    }

    // Dot with A: s = sum_k A[pw+k][q0+lane] * m[k]  (coalesced dword loads, L2-hot)
    float s = 0.f;
    #pragma unroll
    for (int k = 0; k < 16; ++k)
        s += Ag[(pw + k) * 128 + q0 + lane] * m[k];

    // Block reduce, one atomic per block
    #pragma unroll
    for (int off = 32; off; off >>= 1) s += __shfl_down(s, off, 64);
    if (lane == 0) red[w] = s;
    __syncthreads();
    if (t == 0) {
        float acc = 0.f;
        #pragma unroll
        for (int k = 0; k < 8; ++k) acc += red[k];
        atomicAdd(&ws[WS_NUM], acc);
    }
}

// ---------------------------------------------------------------------------
// finalize: loss = -(num / B) / max(total_weight, 1e-8)
// ---------------------------------------------------------------------------
__global__ void finalize_kernel(const float* __restrict__ ws,
                                float* __restrict__ out) {
    const float tw = fmaxf(ws[WS_TW], 1e-8f);
    out[0] = -ws[WS_NUM] / ((float)NB * tw);
}

extern "C" void kernel_launch(void* const* d_in, const int* in_sizes, int n_in,
                              void* d_out, int out_size, void* d_ws, size_t ws_size,
                              hipStream_t stream) {
    const float* P    = (const float*)d_in[0];
    const float* dhw  = (const float*)d_in[1];
    const float* derr = (const float*)d_in[2];
    const int*   prs  = (const int*)d_in[3];
    const float* wts  = (const float*)d_in[4];
    float* ws  = (float*)d_ws;
    float* out = (float*)d_out;

    hipMemsetAsync(ws, 0, (WS_NUM + 1) * sizeof(float), stream);
    prep_kernel<<<NE / 256, 256, 0, stream>>>(dhw, derr, prs, wts, ws);
    batch_kernel<<<NB * 8, 512, 0, stream>>>(P, ws);
    finalize_kernel<<<1, 1, 0, stream>>>(ws, out);
}

// Round 5
// 30.839 us; speedup vs baseline: 1.9310x; 1.1410x over previous
//
#include <hip/hip_runtime.h>

// Problem constants
#define NB 64
#define NL 128
#define NQ 128
#define NE 16384

// ws float layout
#define WS_W    0          // [i][j] row-major W (edge-weight scatter)
#define WS_TW   16384      // total weight
#define WS_NUM  16385      // numerator accumulator
#define WS_AT   16388      // [q][p] A_fid transposed (16B aligned: 16388*4%16==0)
#define WS_END  (WS_AT + 16384)

using short8 = __attribute__((ext_vector_type(8))) short;  // 8 bf16 (4 VGPRs)
using f32x4  = __attribute__((ext_vector_type(4))) float;  // 4 fp32 acc

// fp32 -> bf16 bits, round-to-nearest-even (truncation would bias loss ~ -6!)
__device__ inline unsigned short f2bf(float f) {
    const unsigned u = __float_as_uint(f);
    return (unsigned short)((u + 0x7fffu + ((u >> 16) & 1u)) >> 16);
}

__device__ inline short8 pack8(float4 a, float4 b) {
    short8 r;
    r[0] = f2bf(a.x); r[1] = f2bf(a.y); r[2] = f2bf(a.z); r[3] = f2bf(a.w);
    r[4] = f2bf(b.x); r[5] = f2bf(b.y); r[6] = f2bf(b.z); r[7] = f2bf(b.w);
    return r;
}

// ---------------------------------------------------------------------------
// prep: build A_fid transposed (At[q][p]), scatter edge weights into W[i][j]
// row-major, reduce total weight. grid = 64 x 256; idx covers 16384 = Q*Q = E.
// ---------------------------------------------------------------------------
__global__ void prep_kernel(const float* __restrict__ dhw,
                            const float* __restrict__ derr,
                            const int* __restrict__ pairs,
                            const float* __restrict__ wts,
                            float* __restrict__ ws) {
    const int idx = blockIdx.x * 256 + threadIdx.x;

    {   // At[q*128+p] = (dhw[p,q]==1) * max(1-derr[p,q],0)
        const float hw = dhw[idx];
        const float er = derr[idx];
        const float a  = (hw == 1.0f) ? fmaxf(1.0f - er, 0.f) : 0.f;
        const int p = idx >> 7, q = idx & 127;
        ws[WS_AT + q * 128 + p] = a;
    }

    const int i = pairs[2 * idx];
    const int j = pairs[2 * idx + 1];
    const float w = wts[idx];
    atomicAdd(&ws[WS_W + i * 128 + j], w);     // row-major W

    float s = w;
    #pragma unroll
    for (int off = 32; off; off >>= 1) s += __shfl_down(s, off, 64);
    __shared__ float red[4];
    const int lane = threadIdx.x & 63, wv = threadIdx.x >> 6;
    if (lane == 0) red[wv] = s;
    __syncthreads();
    if (threadIdx.x == 0)
        atomicAdd(&ws[WS_TW], red[0] + red[1] + red[2] + red[3]);
}

// ---------------------------------------------------------------------------
// batch (MFMA): block = (b, 16-row i-tile); 512 blocks x 256 threads (4 waves).
// Wave wv handles q-tiles {wv*2, wv*2+1}. Per (i-tile, q-tile):
//   accG = sum_k mfma(Wfrag, Pfrag)   -> G = W * P_b    (16x16, K=128)
//   accY = sum_k mfma(Pfrag, Atfrag)  -> Y = P_b * A
//   s   += <accG, accY>   (C-layout-invariant elementwise dot)
// No LDS staging, no mid-kernel barriers; all operands L2/L3-hot.
// ---------------------------------------------------------------------------
__global__ __launch_bounds__(256) void batch_kernel(const float* __restrict__ P,
                                                    float* __restrict__ ws) {
    const int blk = blockIdx.x;            // 512 = 64 b * 8 i-tiles
    const int b   = blk >> 3;
    const int i0  = (blk & 7) * 16;
    const float* __restrict__ Pb = P + b * (NL * NQ);
    const float* __restrict__ Wg = ws + WS_W;
    const float* __restrict__ At = ws + WS_AT;

    const int t    = threadIdx.x;
    const int wv   = t >> 6;
    const int lane = t & 63;
    const int mrow = i0 + (lane & 15);     // M-side row (same conv for W and P)
    const int kb   = (lane >> 4) * 8;      // K-side lane offset (same conv A & B)

    // Hoisted A-operand fragments: W rows (for G) and P rows (for Y), 4 k-steps
    short8 WA[4], PA[4];
    #pragma unroll
    for (int kk = 0; kk < 4; ++kk) {
        const int k0 = kk * 32 + kb;
        const float4 w0 = *(const float4*)&Wg[mrow * 128 + k0];
        const float4 w1 = *(const float4*)&Wg[mrow * 128 + k0 + 4];
        WA[kk] = pack8(w0, w1);
        const float4 p0 = *(const float4*)&Pb[mrow * 128 + k0];
        const float4 p1 = *(const float4*)&Pb[mrow * 128 + k0 + 4];
        PA[kk] = pack8(p0, p1);
    }

    float s = 0.f;
    #pragma unroll
    for (int c = 0; c < 2; ++c) {
        const int q0   = (wv * 2 + c) * 16;
        const int ncol = q0 + (lane & 15); // N-side col (same conv both GEMMs)
        f32x4 accG = {0.f, 0.f, 0.f, 0.f};
        f32x4 accY = {0.f, 0.f, 0.f, 0.f};
        #pragma unroll
        for (int kk = 0; kk < 4; ++kk) {
            const int k0 = kk * 32 + kb;
            // G B-frag: P_b[j][ncol], j = k0..k0+7 (column gather, L2-hot)
            short8 gb;
            gb[0] = f2bf(Pb[(k0 + 0) * 128 + ncol]);
            gb[1] = f2bf(Pb[(k0 + 1) * 128 + ncol]);
            gb[2] = f2bf(Pb[(k0 + 2) * 128 + ncol]);
            gb[3] = f2bf(Pb[(k0 + 3) * 128 + ncol]);
            gb[4] = f2bf(Pb[(k0 + 4) * 128 + ncol]);
            gb[5] = f2bf(Pb[(k0 + 5) * 128 + ncol]);
            gb[6] = f2bf(Pb[(k0 + 6) * 128 + ncol]);
            gb[7] = f2bf(Pb[(k0 + 7) * 128 + ncol]);
            accG = __builtin_amdgcn_mfma_f32_16x16x32_bf16(WA[kk], gb, accG, 0, 0, 0);
            // Y B-frag: At[ncol][k0..k0+7] (contiguous)
            const float4 a0 = *(const float4*)&At[ncol * 128 + k0];
            const float4 a1 = *(const float4*)&At[ncol * 128 + k0 + 4];
            accY = __builtin_amdgcn_mfma_f32_16x16x32_bf16(PA[kk], pack8(a0, a1),
                                                           accY, 0, 0, 0);
        }
        s += accG[0] * accY[0] + accG[1] * accY[1]
           + accG[2] * accY[2] + accG[3] * accY[3];
    }

    // Block reduce, one atomic per block
    #pragma unroll
    for (int off = 32; off; off >>= 1) s += __shfl_down(s, off, 64);
    __shared__ float red[4];
    if (lane == 0) red[wv] = s;
    __syncthreads();
    if (t == 0) atomicAdd(&ws[WS_NUM], red[0] + red[1] + red[2] + red[3]);
}

// ---------------------------------------------------------------------------
// finalize: loss = -(num / B) / max(total_weight, 1e-8)
// ---------------------------------------------------------------------------
__global__ void finalize_kernel(const float* __restrict__ ws,
                                float* __restrict__ out) {
    const float tw = fmaxf(ws[WS_TW], 1e-8f);
    out[0] = -ws[WS_NUM] / ((float)NB * tw);
}

extern "C" void kernel_launch(void* const* d_in, const int* in_sizes, int n_in,
                              void* d_out, int out_size, void* d_ws, size_t ws_size,
                              hipStream_t stream) {
    const float* P    = (const float*)d_in[0];
    const float* dhw  = (const float*)d_in[1];
    const float* derr = (const float*)d_in[2];
    const int*   prs  = (const int*)d_in[3];
    const float* wts  = (const float*)d_in[4];
    float* ws  = (float*)d_ws;
    float* out = (float*)d_out;

    hipMemsetAsync(ws, 0, (WS_NUM + 1) * sizeof(float), stream);
    prep_kernel<<<NE / 256, 256, 0, stream>>>(dhw, derr, prs, wts, ws);
    batch_kernel<<<NB * 8, 256, 0, stream>>>(P, ws);
    finalize_kernel<<<1, 1, 0, stream>>>(ws, out);
}